// Round 13
// baseline (40.570 us; speedup 1.0000x reference)
//
#include <hip/hip_runtime.h>
#include <stdint.h>

// Problem constants
constexpr int Dn = 10000;
constexpr int Bn = 128;
constexpr int Wn = 512;
constexpr int Hn = 128;
constexpr int NTD = 625;         // d-subtiles of 16
constexpr int REPS = 4;          // attribution: repeat idempotent compute body

typedef float  f32x4  __attribute__((ext_vector_type(4)));
typedef short  bf16x8 __attribute__((ext_vector_type(8)));  // 8 bf16 (4 VGPRs)

__device__ inline uint16_t f32_to_bf16(float f) {           // RNE
    uint32_t u = __builtin_bit_cast(uint32_t, f);
    return (uint16_t)((u + 0x7FFFu + ((u >> 16) & 1u)) >> 16);
}
__device__ inline float bf16_to_f32(uint16_t h) {
    uint32_t u = ((uint32_t)h) << 16;
    return __builtin_bit_cast(float, u);
}

// ---------------------------------------------------------------------------
// Kernel 1 (fused pre-pass) — identical to R9/R11 (proven absmax 0):
//  blocks 0..511  : h-reduction -> sT64[b][w] + aHi/aLo (MFMA A-fragment
//                   layout, bf16 hi/lo split).
//  blocks 512..1136: pack W signs transposed: bitsT[d*16+g] bit j =
//                   (W[g*32+j][d] > 0), 64 B contiguous per d.
// ---------------------------------------------------------------------------
__global__ __launch_bounds__(256) void prep(const float* __restrict__ x,
                                            const float* __restrict__ wts,
                                            double* __restrict__ sT64,
                                            uint16_t* __restrict__ aHi,
                                            uint16_t* __restrict__ aLo,
                                            uint32_t* __restrict__ bitsT) {
    int bid = blockIdx.x;
    if (bid < 512) {
        int b  = bid >> 2;
        int w0 = (bid & 3) << 7;            // w-quarter base
        int wc = threadIdx.x & 31;          // float4 column: w = w0 + wc*4
        int hs = threadIdx.x >> 5;          // 8 h-slices of 16
        const f32x4* p = (const f32x4*)(x + (size_t)b * (Hn * Wn)
                                          + (size_t)(hs * 16) * Wn + w0) + wc;
        double a0 = 0, a1 = 0, a2 = 0, a3 = 0;
        #pragma unroll
        for (int h = 0; h < 16; ++h) {
            f32x4 f = p[(size_t)h * (Wn / 4)];
            a0 += (double)f.x; a1 += (double)f.y;
            a2 += (double)f.z; a3 += (double)f.w;
        }
        __shared__ double red[8][128];
        red[hs][wc * 4 + 0] = a0;
        red[hs][wc * 4 + 1] = a1;
        red[hs][wc * 4 + 2] = a2;
        red[hs][wc * 4 + 3] = a3;
        __syncthreads();
        if (threadIdx.x < 128) {
            int wl = threadIdx.x;
            double s = 0.0;
            #pragma unroll
            for (int k = 0; k < 8; ++k) s += red[k][wl];   // fixed order
            int w = w0 + wl;
            sT64[(size_t)b * Wn + w] = s;
            float s32 = (float)s;
            uint16_t hi = f32_to_bf16(s32);
            float hif = bf16_to_f32(hi);
            uint16_t lo = f32_to_bf16(s32 - hif);          // residual capture
            int ktile = w >> 5;
            int mtile = b >> 4;
            int lane  = (b & 15) | (((w >> 3) & 3) << 4);
            int j     = w & 7;
            size_t idx = (size_t)((ktile * 8 + mtile) * 64 + lane) * 8 + j;
            aHi[idx] = hi;
            aLo[idx] = lo;
        }
    } else {
        int idx = (bid - 512) * 256 + (int)threadIdx.x;    // 0 .. 159999 exactly
        int g = idx / Dn;
        int d = idx - g * Dn;
        uint32_t m = 0;
        #pragma unroll
        for (int j = 0; j < 32; ++j)
            m |= (wts[(size_t)(g * 32 + j) * Dn + d] > 0.0f) ? (1u << j) : 0u;
        bitsT[(size_t)d * 16 + g] = m;                     // transposed layout
    }
}

// ---------------------------------------------------------------------------
// Kernel 2: MFMA GEMM — R12's occupancy shape + R11's bit-synth B path,
// compute body wrapped in REPS for attribution.
// grid (157, 8), 256 threads = 4 waves. Block stages its mt's 32 KB A-slice
// into LDS once (barrier outside REPS). Wave w owns the nt=w 16-d column
// slice of d-tile blockIdx.x: wrd[16] mask words (16 VGPR), per g:
// 2 ds_read_b128 (conflict-free) + ~10 VALU B-synth + 2 MFMA.
// __launch_bounds__(256,4) -> VGPR <= 128 (kernel needs ~70), 4 blocks/CU.
// Epilogue: sign store + __ballot ambiguous (|v|<=0.25), wave-cooperative
// fp64 exact recompute (proven R9/R11/R12), owner-lane overwrite.
// ---------------------------------------------------------------------------
__global__ __launch_bounds__(256, 4) void gemm_mfma(const uint32_t* __restrict__ bitsT,
                                                    const uint16_t* __restrict__ aHi,
                                                    const uint16_t* __restrict__ aLo,
                                                    const double* __restrict__ sT64,
                                                    float* __restrict__ out) {
    __shared__ uint4 shA[2048];              // 32 KB: chunks 0..15 hi, 16..31 lo
    int tid  = (int)threadIdx.x;
    int lane = tid & 63;
    int wid  = tid >> 6;                     // nt = wid
    int mt   = blockIdx.y;                   // b-range mt*16..+15
    int t    = blockIdx.x;                   // d-tile (N=64)

    // --- cooperative A staging (chunk g = 1 KB = 64 lanes x 16 B) ---
    const uint4* AhU = (const uint4*)aHi;    // fragment (g,mt): base (g*8+mt)*64
    const uint4* AlU = (const uint4*)aLo;
    #pragma unroll
    for (int c = 0; c < 8; ++c) {
        int e = tid + 256 * c;               // 0..2047
        int chunk = e >> 6;                  // 0..31
        int l = e & 63;
        int g = chunk & 15;
        const uint4* src = (chunk < 16 ? AhU : AlU) + (size_t)(g * 8 + mt) * 64 + l;
        shA[e] = *src;
    }

    // --- per-wave mask-word preload (wave's own 16-d column slice) ---
    int ln = lane & 15;
    int lh = lane >> 4;
    int sh = lh * 8;
    int d = t * 64 + wid * 16 + ln;
    int dc = d < Dn ? d : Dn - 1;            // clamp (tail tile only)
    uint32_t wrd[16];
    {
        const uint4* wp = (const uint4*)(bitsT + (size_t)dc * 16);
        #pragma unroll
        for (int q = 0; q < 4; ++q) {
            uint4 v = wp[q];
            wrd[4 * q + 0] = v.x; wrd[4 * q + 1] = v.y;
            wrd[4 * q + 2] = v.z; wrd[4 * q + 3] = v.w;
        }
    }

    __syncthreads();                         // A staged (once; reps reuse it)

    const bf16x8* shAv = (const bf16x8*)shA;
    bool valid = d < Dn;

    for (int rep = 0; rep < REPS; ++rep) {
        asm volatile("" ::: "memory");       // force real re-reads per rep

        f32x4 acc = (f32x4){0.f, 0.f, 0.f, 0.f};
        #pragma unroll
        for (int g = 0; g < 16; ++g) {
            bf16x8 ah = shAv[g * 64 + lane];         // ds_read_b128
            bf16x8 al = shAv[(16 + g) * 64 + lane];
            uint32_t t8 = (wrd[g] >> sh) & 0xFFu;
            // bit=1 -> +1.0 (0x3F80), bit=0 -> -1.0 (0xBF80): XOR sign bit
            int bw0 = (int)(0xBF80BF80u ^ (((t8 & 1u) << 15) | ((t8 & 2u) << 30)));
            int bw1 = (int)(0xBF80BF80u ^ ((((t8 >> 2) & 1u) << 15) | (((t8 >> 3) & 1u) << 31)));
            int bw2 = (int)(0xBF80BF80u ^ ((((t8 >> 4) & 1u) << 15) | (((t8 >> 5) & 1u) << 31)));
            int bw3 = (int)(0xBF80BF80u ^ ((((t8 >> 6) & 1u) << 15) | (((t8 >> 7) & 1u) << 31)));
            union { int i[4]; bf16x8 v; } bu;
            bu.i[0] = bw0; bu.i[1] = bw1; bu.i[2] = bw2; bu.i[3] = bw3;
            bf16x8 bf = bu.v;
            acc = __builtin_amdgcn_mfma_f32_16x16x32_bf16(ah, bf, acc, 0, 0, 0);
            acc = __builtin_amdgcn_mfma_f32_16x16x32_bf16(al, bf, acc, 0, 0, 0);
        }

        // Epilogue. C/D layout: col = lane&15, row = (lane>>4)*4 + reg.
        #pragma unroll
        for (int r = 0; r < 4; ++r) {
            int b = mt * 16 + lh * 4 + r;
            float v = acc[r];
            if (valid) out[(size_t)b * Dn + d] = v > 0.0f ? 1.0f : -1.0f;
            unsigned long long mask = __ballot(valid && fabsf(v) <= 0.25f);
            while (mask) {
                int l = __ffsll((long long)mask) - 1;
                mask &= mask - 1;
                int bl = mt * 16 + (l >> 4) * 4 + r;
                int dl = t * 64 + wid * 16 + (l & 15);
                const double* srow = sT64 + (size_t)bl * Wn;
                double a = 0.0;
                #pragma unroll
                for (int k = 0; k < 8; ++k) {
                    int w = lane + 64 * k;
                    uint32_t mw = bitsT[(size_t)dl * 16 + (w >> 5)];
                    double s = srow[w];
                    a += ((mw >> (w & 31)) & 1u) ? s : -s;
                }
                #pragma unroll
                for (int off = 32; off >= 1; off >>= 1)
                    a += __shfl_xor(a, off, 64);
                if (lane == l)          // owner overwrites its own guess
                    out[(size_t)bl * Dn + dl] = (a > 0.0) ? 1.0f : ((a < 0.0) ? -1.0f : 0.0f);
            }
        }
    }
}

// ---------------------------------------------------------------------------
extern "C" void kernel_launch(void* const* d_in, const int* in_sizes, int n_in,
                              void* d_out, int out_size, void* d_ws, size_t ws_size,
                              hipStream_t stream) {
    const float* x   = (const float*)d_in[0];   // (128,128,512) f32
    const float* wts = (const float*)d_in[1];   // (512,10000)  f32, values +-1
    float* out = (float*)d_out;                 // (128,10000)  f32 signs
    char* ws = (char*)d_ws;

    // workspace layout (~1.43 MB total)
    double*   sT64  = (double*)(ws);                  // 128*512*8 = 524,288 B
    uint16_t* aHi   = (uint16_t*)(ws + 524288);       // 131,072 B
    uint16_t* aLo   = (uint16_t*)(ws + 655360);       // 131,072 B
    uint32_t* bitsT = (uint32_t*)(ws + 786432);       // 640,000 B

    prep<<<1137, 256, 0, stream>>>(x, wts, sT64, aHi, aLo, bitsT);
    gemm_mfma<<<dim3(157, 8), 256, 0, stream>>>(bitsT, aHi, aLo, sT64, out);
}

// Round 14
// 24.693 us; speedup vs baseline: 1.6430x; 1.6430x over previous
//
#include <hip/hip_runtime.h>
#include <stdint.h>

// Problem constants
constexpr int Dn = 10000;
constexpr int Bn = 128;
constexpr int Wn = 512;
constexpr int Hn = 128;

typedef float  f32x4  __attribute__((ext_vector_type(4)));
typedef short  bf16x8 __attribute__((ext_vector_type(8)));  // 8 bf16 (4 VGPRs)

__device__ inline uint16_t f32_to_bf16(float f) {           // RNE
    uint32_t u = __builtin_bit_cast(uint32_t, f);
    return (uint16_t)((u + 0x7FFFu + ((u >> 16) & 1u)) >> 16);
}
__device__ inline float bf16_to_f32(uint16_t h) {
    uint32_t u = ((uint32_t)h) << 16;
    return __builtin_bit_cast(float, u);
}

// ---------------------------------------------------------------------------
// Kernel 1 (fused pre-pass) — identical to R9/R11/R13 (proven absmax 0):
//  blocks 0..511  : h-reduction -> sT64[b][w] + aHi/aLo (MFMA A-fragment
//                   layout, bf16 hi/lo split).
//  blocks 512..1136: pack W signs transposed: bitsT[d*16+g] bit j =
//                   (W[g*32+j][d] > 0), 64 B contiguous per d.
// ---------------------------------------------------------------------------
__global__ __launch_bounds__(256) void prep(const float* __restrict__ x,
                                            const float* __restrict__ wts,
                                            double* __restrict__ sT64,
                                            uint16_t* __restrict__ aHi,
                                            uint16_t* __restrict__ aLo,
                                            uint32_t* __restrict__ bitsT) {
    int bid = blockIdx.x;
    if (bid < 512) {
        int b  = bid >> 2;
        int w0 = (bid & 3) << 7;            // w-quarter base
        int wc = threadIdx.x & 31;          // float4 column: w = w0 + wc*4
        int hs = threadIdx.x >> 5;          // 8 h-slices of 16
        const f32x4* p = (const f32x4*)(x + (size_t)b * (Hn * Wn)
                                          + (size_t)(hs * 16) * Wn + w0) + wc;
        double a0 = 0, a1 = 0, a2 = 0, a3 = 0;
        #pragma unroll
        for (int h = 0; h < 16; ++h) {
            f32x4 f = p[(size_t)h * (Wn / 4)];
            a0 += (double)f.x; a1 += (double)f.y;
            a2 += (double)f.z; a3 += (double)f.w;
        }
        __shared__ double red[8][128];
        red[hs][wc * 4 + 0] = a0;
        red[hs][wc * 4 + 1] = a1;
        red[hs][wc * 4 + 2] = a2;
        red[hs][wc * 4 + 3] = a3;
        __syncthreads();
        if (threadIdx.x < 128) {
            int wl = threadIdx.x;
            double s = 0.0;
            #pragma unroll
            for (int k = 0; k < 8; ++k) s += red[k][wl];   // fixed order
            int w = w0 + wl;
            sT64[(size_t)b * Wn + w] = s;
            float s32 = (float)s;
            uint16_t hi = f32_to_bf16(s32);
            float hif = bf16_to_f32(hi);
            uint16_t lo = f32_to_bf16(s32 - hif);          // residual capture
            int ktile = w >> 5;
            int mtile = b >> 4;
            int lane  = (b & 15) | (((w >> 3) & 3) << 4);
            int j     = w & 7;
            size_t idx = (size_t)((ktile * 8 + mtile) * 64 + lane) * 8 + j;
            aHi[idx] = hi;
            aLo[idx] = lo;
        }
    } else {
        int idx = (bid - 512) * 256 + (int)threadIdx.x;    // 0 .. 159999 exactly
        int g = idx / Dn;
        int d = idx - g * Dn;
        uint32_t m = 0;
        #pragma unroll
        for (int j = 0; j < 32; ++j)
            m |= (wts[(size_t)(g * 32 + j) * Dn + d] > 0.0f) ? (1u << j) : 0u;
        bitsT[(size_t)d * 16 + g] = m;                     // transposed layout
    }
}

// ---------------------------------------------------------------------------
// Kernel 2: MFMA GEMM — R13 structure, single pass (REPS removed).
// grid (157, 8), 256 threads = 4 waves. Block stages its mt's 32 KB A-slice
// into LDS once (one barrier). Wave w owns the nt=w 16-d column slice of
// d-tile blockIdx.x: wrd[16] mask words (16 VGPR); per g: 2 ds_read_b128
// (conflict-free) + ~14 VALU bit->+-1 synth + 2 MFMA into one acc chain.
// __launch_bounds__(256,4) -> VGPR <= 128, 4 blocks/CU, ~5024 waves.
// Epilogue: sign store + __ballot ambiguous (|v|<=0.25), wave-cooperative
// fp64 exact recompute from sT64/bitsT, owner-lane overwrite (proven).
// ---------------------------------------------------------------------------
__global__ __launch_bounds__(256, 4) void gemm_mfma(const uint32_t* __restrict__ bitsT,
                                                    const uint16_t* __restrict__ aHi,
                                                    const uint16_t* __restrict__ aLo,
                                                    const double* __restrict__ sT64,
                                                    float* __restrict__ out) {
    __shared__ uint4 shA[2048];              // 32 KB: chunks 0..15 hi, 16..31 lo
    int tid  = (int)threadIdx.x;
    int lane = tid & 63;
    int wid  = tid >> 6;                     // nt = wid
    int mt   = blockIdx.y;                   // b-range mt*16..+15
    int t    = blockIdx.x;                   // d-tile (N=64)

    // --- cooperative A staging (chunk g = 1 KB = 64 lanes x 16 B) ---
    const uint4* AhU = (const uint4*)aHi;    // fragment (g,mt): base (g*8+mt)*64
    const uint4* AlU = (const uint4*)aLo;
    #pragma unroll
    for (int c = 0; c < 8; ++c) {
        int e = tid + 256 * c;               // 0..2047
        int chunk = e >> 6;                  // 0..31
        int l = e & 63;
        int g = chunk & 15;
        const uint4* src = (chunk < 16 ? AhU : AlU) + (size_t)(g * 8 + mt) * 64 + l;
        shA[e] = *src;
    }

    // --- per-wave mask-word preload (wave's own 16-d column slice) ---
    int ln = lane & 15;
    int lh = lane >> 4;
    int sh = lh * 8;
    int d = t * 64 + wid * 16 + ln;
    int dc = d < Dn ? d : Dn - 1;            // clamp (tail tile only)
    uint32_t wrd[16];
    {
        const uint4* wp = (const uint4*)(bitsT + (size_t)dc * 16);
        #pragma unroll
        for (int q = 0; q < 4; ++q) {
            uint4 v = wp[q];
            wrd[4 * q + 0] = v.x; wrd[4 * q + 1] = v.y;
            wrd[4 * q + 2] = v.z; wrd[4 * q + 3] = v.w;
        }
    }

    __syncthreads();                         // A staged

    const bf16x8* shAv = (const bf16x8*)shA;
    bool valid = d < Dn;

    f32x4 acc = (f32x4){0.f, 0.f, 0.f, 0.f};
    #pragma unroll
    for (int g = 0; g < 16; ++g) {
        bf16x8 ah = shAv[g * 64 + lane];         // ds_read_b128
        bf16x8 al = shAv[(16 + g) * 64 + lane];
        uint32_t t8 = (wrd[g] >> sh) & 0xFFu;
        // bit=1 -> +1.0 (0x3F80), bit=0 -> -1.0 (0xBF80): XOR sign bit
        int bw0 = (int)(0xBF80BF80u ^ (((t8 & 1u) << 15) | ((t8 & 2u) << 30)));
        int bw1 = (int)(0xBF80BF80u ^ ((((t8 >> 2) & 1u) << 15) | (((t8 >> 3) & 1u) << 31)));
        int bw2 = (int)(0xBF80BF80u ^ ((((t8 >> 4) & 1u) << 15) | (((t8 >> 5) & 1u) << 31)));
        int bw3 = (int)(0xBF80BF80u ^ ((((t8 >> 6) & 1u) << 15) | (((t8 >> 7) & 1u) << 31)));
        union { int i[4]; bf16x8 v; } bu;
        bu.i[0] = bw0; bu.i[1] = bw1; bu.i[2] = bw2; bu.i[3] = bw3;
        bf16x8 bf = bu.v;
        acc = __builtin_amdgcn_mfma_f32_16x16x32_bf16(ah, bf, acc, 0, 0, 0);
        acc = __builtin_amdgcn_mfma_f32_16x16x32_bf16(al, bf, acc, 0, 0, 0);
    }

    // Epilogue. C/D layout: col = lane&15, row = (lane>>4)*4 + reg.
    #pragma unroll
    for (int r = 0; r < 4; ++r) {
        int b = mt * 16 + lh * 4 + r;
        float v = acc[r];
        if (valid) out[(size_t)b * Dn + d] = v > 0.0f ? 1.0f : -1.0f;
        unsigned long long mask = __ballot(valid && fabsf(v) <= 0.25f);
        while (mask) {
            int l = __ffsll((long long)mask) - 1;
            mask &= mask - 1;
            int bl = mt * 16 + (l >> 4) * 4 + r;
            int dl = t * 64 + wid * 16 + (l & 15);
            const double* srow = sT64 + (size_t)bl * Wn;
            double a = 0.0;
            #pragma unroll
            for (int k = 0; k < 8; ++k) {
                int w = lane + 64 * k;
                uint32_t mw = bitsT[(size_t)dl * 16 + (w >> 5)];
                double s = srow[w];
                a += ((mw >> (w & 31)) & 1u) ? s : -s;
            }
            #pragma unroll
            for (int off = 32; off >= 1; off >>= 1)
                a += __shfl_xor(a, off, 64);
            if (lane == l)          // owner overwrites its own guess
                out[(size_t)bl * Dn + dl] = (a > 0.0) ? 1.0f : ((a < 0.0) ? -1.0f : 0.0f);
        }
    }
}

// ---------------------------------------------------------------------------
extern "C" void kernel_launch(void* const* d_in, const int* in_sizes, int n_in,
                              void* d_out, int out_size, void* d_ws, size_t ws_size,
                              hipStream_t stream) {
    const float* x   = (const float*)d_in[0];   // (128,128,512) f32
    const float* wts = (const float*)d_in[1];   // (512,10000)  f32, values +-1
    float* out = (float*)d_out;                 // (128,10000)  f32 signs
    char* ws = (char*)d_ws;

    // workspace layout (~1.43 MB total)
    double*   sT64  = (double*)(ws);                  // 128*512*8 = 524,288 B
    uint16_t* aHi   = (uint16_t*)(ws + 524288);       // 131,072 B
    uint16_t* aLo   = (uint16_t*)(ws + 655360);       // 131,072 B
    uint32_t* bitsT = (uint32_t*)(ws + 786432);       // 640,000 B

    prep<<<1137, 256, 0, stream>>>(x, wts, sT64, aHi, aLo, bitsT);
    gemm_mfma<<<dim3(157, 8), 256, 0, stream>>>(bitsT, aHi, aLo, sT64, out);
}

// Round 15
// 24.372 us; speedup vs baseline: 1.6646x; 1.0132x over previous
//
#include <hip/hip_runtime.h>
#include <stdint.h>

// Problem constants
constexpr int Dn = 10000;
constexpr int Bn = 128;
constexpr int Wn = 512;
constexpr int Hn = 128;
constexpr int NBLK = 1256;       // 157 d-tiles x 8 mt

typedef float  f32x4  __attribute__((ext_vector_type(4)));
typedef short  bf16x8 __attribute__((ext_vector_type(8)));  // 8 bf16 (4 VGPRs)

__device__ inline uint16_t f32_to_bf16(float f) {           // RNE
    uint32_t u = __builtin_bit_cast(uint32_t, f);
    return (uint16_t)((u + 0x7FFFu + ((u >> 16) & 1u)) >> 16);
}
__device__ inline float bf16_to_f32(uint16_t h) {
    uint32_t u = ((uint32_t)h) << 16;
    return __builtin_bit_cast(float, u);
}

// ---------------------------------------------------------------------------
// Kernel 1 (fused pre-pass) — identical to R9..R14 (proven absmax 0):
//  blocks 0..511  : h-reduction -> sT64[b][w] + aHi/aLo (MFMA A-fragment
//                   layout, bf16 hi/lo split).
//  blocks 512..1136: pack W signs transposed: bitsT[d*16+g] bit j =
//                   (W[g*32+j][d] > 0), 64 B contiguous per d.
// ---------------------------------------------------------------------------
__global__ __launch_bounds__(256) void prep(const float* __restrict__ x,
                                            const float* __restrict__ wts,
                                            double* __restrict__ sT64,
                                            uint16_t* __restrict__ aHi,
                                            uint16_t* __restrict__ aLo,
                                            uint32_t* __restrict__ bitsT) {
    int bid = blockIdx.x;
    if (bid < 512) {
        int b  = bid >> 2;
        int w0 = (bid & 3) << 7;            // w-quarter base
        int wc = threadIdx.x & 31;          // float4 column: w = w0 + wc*4
        int hs = threadIdx.x >> 5;          // 8 h-slices of 16
        const f32x4* p = (const f32x4*)(x + (size_t)b * (Hn * Wn)
                                          + (size_t)(hs * 16) * Wn + w0) + wc;
        double a0 = 0, a1 = 0, a2 = 0, a3 = 0;
        #pragma unroll
        for (int h = 0; h < 16; ++h) {
            f32x4 f = p[(size_t)h * (Wn / 4)];
            a0 += (double)f.x; a1 += (double)f.y;
            a2 += (double)f.z; a3 += (double)f.w;
        }
        __shared__ double red[8][128];
        red[hs][wc * 4 + 0] = a0;
        red[hs][wc * 4 + 1] = a1;
        red[hs][wc * 4 + 2] = a2;
        red[hs][wc * 4 + 3] = a3;
        __syncthreads();
        if (threadIdx.x < 128) {
            int wl = threadIdx.x;
            double s = 0.0;
            #pragma unroll
            for (int k = 0; k < 8; ++k) s += red[k][wl];   // fixed order
            int w = w0 + wl;
            sT64[(size_t)b * Wn + w] = s;
            float s32 = (float)s;
            uint16_t hi = f32_to_bf16(s32);
            float hif = bf16_to_f32(hi);
            uint16_t lo = f32_to_bf16(s32 - hif);          // residual capture
            int ktile = w >> 5;
            int mtile = b >> 4;
            int lane  = (b & 15) | (((w >> 3) & 3) << 4);
            int j     = w & 7;
            size_t idx = (size_t)((ktile * 8 + mtile) * 64 + lane) * 8 + j;
            aHi[idx] = hi;
            aLo[idx] = lo;
        }
    } else {
        int idx = (bid - 512) * 256 + (int)threadIdx.x;    // 0 .. 159999 exactly
        int g = idx / Dn;
        int d = idx - g * Dn;
        uint32_t m = 0;
        #pragma unroll
        for (int j = 0; j < 32; ++j)
            m |= (wts[(size_t)(g * 32 + j) * Dn + d] > 0.0f) ? (1u << j) : 0u;
        bitsT[(size_t)d * 16 + g] = m;                     // transposed layout
    }
}

// ---------------------------------------------------------------------------
// Kernel 2: MFMA GEMM — R14 structure + XCD-aware block swizzle.
// Flat grid 1256; mt = id & 7, t = id >> 3. Linear block IDs round-robin
// across the 8 XCDs, so all 157 blocks sharing an mt (and hence the same
// 32 KB A-slice) land on ONE XCD: the slice is L3-fetched once, then
// L2-local for the other 156 blocks. (Decode is a bijection -- if the
// HW mapping differs this is performance-neutral, Guide §1.)
// Per block: stage A-slice to LDS (one barrier); wave w owns the nt=w 16-d
// column slice of d-tile t: wrd[16] masks; per g: 2 ds_read_b128 + bit->+-1
// synth + 2 MFMA. Epilogue: sign store + __ballot ambiguous (|v|<=0.25),
// wave-cooperative fp64 exact recompute, owner-lane overwrite (proven).
// ---------------------------------------------------------------------------
__global__ __launch_bounds__(256, 4) void gemm_mfma(const uint32_t* __restrict__ bitsT,
                                                    const uint16_t* __restrict__ aHi,
                                                    const uint16_t* __restrict__ aLo,
                                                    const double* __restrict__ sT64,
                                                    float* __restrict__ out) {
    __shared__ uint4 shA[2048];              // 32 KB: chunks 0..15 hi, 16..31 lo
    int tid  = (int)threadIdx.x;
    int lane = tid & 63;
    int wid  = tid >> 6;                     // nt = wid
    int id   = blockIdx.x;
    int mt   = id & 7;                       // XCD-locality: same mt -> same XCD
    int t    = id >> 3;                      // d-tile (N=64)

    // --- cooperative A staging (chunk g = 1 KB = 64 lanes x 16 B) ---
    const uint4* AhU = (const uint4*)aHi;    // fragment (g,mt): base (g*8+mt)*64
    const uint4* AlU = (const uint4*)aLo;
    #pragma unroll
    for (int c = 0; c < 8; ++c) {
        int e = tid + 256 * c;               // 0..2047
        int chunk = e >> 6;                  // 0..31
        int l = e & 63;
        int g = chunk & 15;
        const uint4* src = (chunk < 16 ? AhU : AlU) + (size_t)(g * 8 + mt) * 64 + l;
        shA[e] = *src;
    }

    // --- per-wave mask-word preload (wave's own 16-d column slice) ---
    int ln = lane & 15;
    int lh = lane >> 4;
    int sh = lh * 8;
    int d = t * 64 + wid * 16 + ln;
    int dc = d < Dn ? d : Dn - 1;            // clamp (tail tile only)
    uint32_t wrd[16];
    {
        const uint4* wp = (const uint4*)(bitsT + (size_t)dc * 16);
        #pragma unroll
        for (int q = 0; q < 4; ++q) {
            uint4 v = wp[q];
            wrd[4 * q + 0] = v.x; wrd[4 * q + 1] = v.y;
            wrd[4 * q + 2] = v.z; wrd[4 * q + 3] = v.w;
        }
    }

    __syncthreads();                         // A staged

    const bf16x8* shAv = (const bf16x8*)shA;
    bool valid = d < Dn;

    f32x4 acc = (f32x4){0.f, 0.f, 0.f, 0.f};
    #pragma unroll
    for (int g = 0; g < 16; ++g) {
        bf16x8 ah = shAv[g * 64 + lane];         // ds_read_b128
        bf16x8 al = shAv[(16 + g) * 64 + lane];
        uint32_t t8 = (wrd[g] >> sh) & 0xFFu;
        // bit=1 -> +1.0 (0x3F80), bit=0 -> -1.0 (0xBF80): XOR sign bit
        int bw0 = (int)(0xBF80BF80u ^ (((t8 & 1u) << 15) | ((t8 & 2u) << 30)));
        int bw1 = (int)(0xBF80BF80u ^ ((((t8 >> 2) & 1u) << 15) | (((t8 >> 3) & 1u) << 31)));
        int bw2 = (int)(0xBF80BF80u ^ ((((t8 >> 4) & 1u) << 15) | (((t8 >> 5) & 1u) << 31)));
        int bw3 = (int)(0xBF80BF80u ^ ((((t8 >> 6) & 1u) << 15) | (((t8 >> 7) & 1u) << 31)));
        union { int i[4]; bf16x8 v; } bu;
        bu.i[0] = bw0; bu.i[1] = bw1; bu.i[2] = bw2; bu.i[3] = bw3;
        bf16x8 bf = bu.v;
        acc = __builtin_amdgcn_mfma_f32_16x16x32_bf16(ah, bf, acc, 0, 0, 0);
        acc = __builtin_amdgcn_mfma_f32_16x16x32_bf16(al, bf, acc, 0, 0, 0);
    }

    // Epilogue. C/D layout: col = lane&15, row = (lane>>4)*4 + reg.
    #pragma unroll
    for (int r = 0; r < 4; ++r) {
        int b = mt * 16 + lh * 4 + r;
        float v = acc[r];
        if (valid) out[(size_t)b * Dn + d] = v > 0.0f ? 1.0f : -1.0f;
        unsigned long long mask = __ballot(valid && fabsf(v) <= 0.25f);
        while (mask) {
            int l = __ffsll((long long)mask) - 1;
            mask &= mask - 1;
            int bl = mt * 16 + (l >> 4) * 4 + r;
            int dl = t * 64 + wid * 16 + (l & 15);
            const double* srow = sT64 + (size_t)bl * Wn;
            double a = 0.0;
            #pragma unroll
            for (int k = 0; k < 8; ++k) {
                int w = lane + 64 * k;
                uint32_t mw = bitsT[(size_t)dl * 16 + (w >> 5)];
                double s = srow[w];
                a += ((mw >> (w & 31)) & 1u) ? s : -s;
            }
            #pragma unroll
            for (int off = 32; off >= 1; off >>= 1)
                a += __shfl_xor(a, off, 64);
            if (lane == l)          // owner overwrites its own guess
                out[(size_t)bl * Dn + dl] = (a > 0.0) ? 1.0f : ((a < 0.0) ? -1.0f : 0.0f);
        }
    }
}

// ---------------------------------------------------------------------------
extern "C" void kernel_launch(void* const* d_in, const int* in_sizes, int n_in,
                              void* d_out, int out_size, void* d_ws, size_t ws_size,
                              hipStream_t stream) {
    const float* x   = (const float*)d_in[0];   // (128,128,512) f32
    const float* wts = (const float*)d_in[1];   // (512,10000)  f32, values +-1
    float* out = (float*)d_out;                 // (128,10000)  f32 signs
    char* ws = (char*)d_ws;

    // workspace layout (~1.43 MB total)
    double*   sT64  = (double*)(ws);                  // 128*512*8 = 524,288 B
    uint16_t* aHi   = (uint16_t*)(ws + 524288);       // 131,072 B
    uint16_t* aLo   = (uint16_t*)(ws + 655360);       // 131,072 B
    uint32_t* bitsT = (uint32_t*)(ws + 786432);       // 640,000 B

    prep<<<1137, 256, 0, stream>>>(x, wts, sT64, aHi, aLo, bitsT);
    gemm_mfma<<<NBLK, 256, 0, stream>>>(bitsT, aHi, aLo, sT64, out);
}

// Round 16
// 24.331 us; speedup vs baseline: 1.6674x; 1.0017x over previous
//
#include <hip/hip_runtime.h>
#include <stdint.h>

// Problem constants
constexpr int Dn = 10000;
constexpr int Bn = 128;
constexpr int Wn = 512;
constexpr int Hn = 128;
constexpr int NBLK = 1256;       // 157 d-tiles x 8 mt

typedef float  f32x4  __attribute__((ext_vector_type(4)));
typedef short  bf16x8 __attribute__((ext_vector_type(8)));  // 8 bf16 (4 VGPRs)

__device__ inline uint16_t f32_to_bf16(float f) {           // RNE
    uint32_t u = __builtin_bit_cast(uint32_t, f);
    return (uint16_t)((u + 0x7FFFu + ((u >> 16) & 1u)) >> 16);
}
__device__ inline float bf16_to_f32(uint16_t h) {
    uint32_t u = ((uint32_t)h) << 16;
    return __builtin_bit_cast(float, u);
}

// ---------------------------------------------------------------------------
// Kernel 1 (fused pre-pass) — identical to R9..R15 (proven absmax 0):
//  blocks 0..511  : h-reduction -> sT64[b][w] + aHi/aLo (MFMA A-fragment
//                   layout, bf16 hi/lo split).
//  blocks 512..1136: pack W signs transposed: bitsT[d*16+g] bit j =
//                   (W[g*32+j][d] > 0), 64 B contiguous per d.
// ---------------------------------------------------------------------------
__global__ __launch_bounds__(256) void prep(const float* __restrict__ x,
                                            const float* __restrict__ wts,
                                            double* __restrict__ sT64,
                                            uint16_t* __restrict__ aHi,
                                            uint16_t* __restrict__ aLo,
                                            uint32_t* __restrict__ bitsT) {
    int bid = blockIdx.x;
    if (bid < 512) {
        int b  = bid >> 2;
        int w0 = (bid & 3) << 7;            // w-quarter base
        int wc = threadIdx.x & 31;          // float4 column: w = w0 + wc*4
        int hs = threadIdx.x >> 5;          // 8 h-slices of 16
        const f32x4* p = (const f32x4*)(x + (size_t)b * (Hn * Wn)
                                          + (size_t)(hs * 16) * Wn + w0) + wc;
        double a0 = 0, a1 = 0, a2 = 0, a3 = 0;
        #pragma unroll
        for (int h = 0; h < 16; ++h) {
            f32x4 f = p[(size_t)h * (Wn / 4)];
            a0 += (double)f.x; a1 += (double)f.y;
            a2 += (double)f.z; a3 += (double)f.w;
        }
        __shared__ double red[8][128];
        red[hs][wc * 4 + 0] = a0;
        red[hs][wc * 4 + 1] = a1;
        red[hs][wc * 4 + 2] = a2;
        red[hs][wc * 4 + 3] = a3;
        __syncthreads();
        if (threadIdx.x < 128) {
            int wl = threadIdx.x;
            double s = 0.0;
            #pragma unroll
            for (int k = 0; k < 8; ++k) s += red[k][wl];   // fixed order
            int w = w0 + wl;
            sT64[(size_t)b * Wn + w] = s;
            float s32 = (float)s;
            uint16_t hi = f32_to_bf16(s32);
            float hif = bf16_to_f32(hi);
            uint16_t lo = f32_to_bf16(s32 - hif);          // residual capture
            int ktile = w >> 5;
            int mtile = b >> 4;
            int lane  = (b & 15) | (((w >> 3) & 3) << 4);
            int j     = w & 7;
            size_t idx = (size_t)((ktile * 8 + mtile) * 64 + lane) * 8 + j;
            aHi[idx] = hi;
            aLo[idx] = lo;
        }
    } else {
        int idx = (bid - 512) * 256 + (int)threadIdx.x;    // 0 .. 159999 exactly
        int g = idx / Dn;
        int d = idx - g * Dn;
        uint32_t m = 0;
        #pragma unroll
        for (int j = 0; j < 32; ++j)
            m |= (wts[(size_t)(g * 32 + j) * Dn + d] > 0.0f) ? (1u << j) : 0u;
        bitsT[(size_t)d * 16 + g] = m;                     // transposed layout
    }
}

// ---------------------------------------------------------------------------
// Kernel 2: MFMA GEMM — R15 structure + single-batch residency + dual acc.
// __launch_bounds__(256,5): 5 blocks/CU x 32 KB LDS = 160 KB exactly -> all
// 1256 blocks co-resident (no second batch; cold staging fully overlapped).
// Flat grid; mt = id & 7 (XCD-local A-slice), t = id >> 3.
// Dual accumulator chains (accH for aHi, accL for aLo, summed in epilogue):
// 2x MFMA ILP; per-chain fp32 error bound still << 0.25 so the proven
// ballot-fixup covers exactness.
// ---------------------------------------------------------------------------
__global__ __launch_bounds__(256, 5) void gemm_mfma(const uint32_t* __restrict__ bitsT,
                                                    const uint16_t* __restrict__ aHi,
                                                    const uint16_t* __restrict__ aLo,
                                                    const double* __restrict__ sT64,
                                                    float* __restrict__ out) {
    __shared__ uint4 shA[2048];              // 32 KB: chunks 0..15 hi, 16..31 lo
    int tid  = (int)threadIdx.x;
    int lane = tid & 63;
    int wid  = tid >> 6;                     // nt = wid
    int id   = blockIdx.x;
    int mt   = id & 7;                       // XCD-locality: same mt -> same XCD
    int t    = id >> 3;                      // d-tile (N=64)

    // --- cooperative A staging (chunk g = 1 KB = 64 lanes x 16 B) ---
    const uint4* AhU = (const uint4*)aHi;    // fragment (g,mt): base (g*8+mt)*64
    const uint4* AlU = (const uint4*)aLo;
    #pragma unroll
    for (int c = 0; c < 8; ++c) {
        int e = tid + 256 * c;               // 0..2047
        int chunk = e >> 6;                  // 0..31
        int l = e & 63;
        int g = chunk & 15;
        const uint4* src = (chunk < 16 ? AhU : AlU) + (size_t)(g * 8 + mt) * 64 + l;
        shA[e] = *src;
    }

    // --- per-wave mask-word preload (wave's own 16-d column slice) ---
    int ln = lane & 15;
    int lh = lane >> 4;
    int sh = lh * 8;
    int d = t * 64 + wid * 16 + ln;
    int dc = d < Dn ? d : Dn - 1;            // clamp (tail tile only)
    uint32_t wrd[16];
    {
        const uint4* wp = (const uint4*)(bitsT + (size_t)dc * 16);
        #pragma unroll
        for (int q = 0; q < 4; ++q) {
            uint4 v = wp[q];
            wrd[4 * q + 0] = v.x; wrd[4 * q + 1] = v.y;
            wrd[4 * q + 2] = v.z; wrd[4 * q + 3] = v.w;
        }
    }

    __syncthreads();                         // A staged

    const bf16x8* shAv = (const bf16x8*)shA;
    bool valid = d < Dn;

    f32x4 accH = (f32x4){0.f, 0.f, 0.f, 0.f};
    f32x4 accL = (f32x4){0.f, 0.f, 0.f, 0.f};
    #pragma unroll
    for (int g = 0; g < 16; ++g) {
        bf16x8 ah = shAv[g * 64 + lane];         // ds_read_b128
        bf16x8 al = shAv[(16 + g) * 64 + lane];
        uint32_t t8 = (wrd[g] >> sh) & 0xFFu;
        // bit=1 -> +1.0 (0x3F80), bit=0 -> -1.0 (0xBF80): XOR sign bit
        int bw0 = (int)(0xBF80BF80u ^ (((t8 & 1u) << 15) | ((t8 & 2u) << 30)));
        int bw1 = (int)(0xBF80BF80u ^ ((((t8 >> 2) & 1u) << 15) | (((t8 >> 3) & 1u) << 31)));
        int bw2 = (int)(0xBF80BF80u ^ ((((t8 >> 4) & 1u) << 15) | (((t8 >> 5) & 1u) << 31)));
        int bw3 = (int)(0xBF80BF80u ^ ((((t8 >> 6) & 1u) << 15) | (((t8 >> 7) & 1u) << 31)));
        union { int i[4]; bf16x8 v; } bu;
        bu.i[0] = bw0; bu.i[1] = bw1; bu.i[2] = bw2; bu.i[3] = bw3;
        bf16x8 bf = bu.v;
        accH = __builtin_amdgcn_mfma_f32_16x16x32_bf16(ah, bf, accH, 0, 0, 0);  // independent
        accL = __builtin_amdgcn_mfma_f32_16x16x32_bf16(al, bf, accL, 0, 0, 0);  // chains
    }

    // Epilogue. C/D layout: col = lane&15, row = (lane>>4)*4 + reg.
    #pragma unroll
    for (int r = 0; r < 4; ++r) {
        int b = mt * 16 + lh * 4 + r;
        float v = accH[r] + accL[r];
        if (valid) out[(size_t)b * Dn + d] = v > 0.0f ? 1.0f : -1.0f;
        unsigned long long mask = __ballot(valid && fabsf(v) <= 0.25f);
        while (mask) {
            int l = __ffsll((long long)mask) - 1;
            mask &= mask - 1;
            int bl = mt * 16 + (l >> 4) * 4 + r;
            int dl = t * 64 + wid * 16 + (l & 15);
            const double* srow = sT64 + (size_t)bl * Wn;
            double a = 0.0;
            #pragma unroll
            for (int k = 0; k < 8; ++k) {
                int w = lane + 64 * k;
                uint32_t mw = bitsT[(size_t)dl * 16 + (w >> 5)];
                double s = srow[w];
                a += ((mw >> (w & 31)) & 1u) ? s : -s;
            }
            #pragma unroll
            for (int off = 32; off >= 1; off >>= 1)
                a += __shfl_xor(a, off, 64);
            if (lane == l)          // owner overwrites its own guess
                out[(size_t)bl * Dn + dl] = (a > 0.0) ? 1.0f : ((a < 0.0) ? -1.0f : 0.0f);
        }
    }
}

// ---------------------------------------------------------------------------
extern "C" void kernel_launch(void* const* d_in, const int* in_sizes, int n_in,
                              void* d_out, int out_size, void* d_ws, size_t ws_size,
                              hipStream_t stream) {
    const float* x   = (const float*)d_in[0];   // (128,128,512) f32
    const float* wts = (const float*)d_in[1];   // (512,10000)  f32, values +-1
    float* out = (float*)d_out;                 // (128,10000)  f32 signs
    char* ws = (char*)d_ws;

    // workspace layout (~1.43 MB total)
    double*   sT64  = (double*)(ws);                  // 128*512*8 = 524,288 B
    uint16_t* aHi   = (uint16_t*)(ws + 524288);       // 131,072 B
    uint16_t* aLo   = (uint16_t*)(ws + 655360);       // 131,072 B
    uint32_t* bitsT = (uint32_t*)(ws + 786432);       // 640,000 B

    prep<<<1137, 256, 0, stream>>>(x, wts, sT64, aHi, aLo, bitsT);
    gemm_mfma<<<NBLK, 256, 0, stream>>>(bitsT, aHi, aLo, sT64, out);
}